// Round 8
// baseline (360.092 us; speedup 1.0000x reference)
//
#include <hip/hip_runtime.h>
#include <hip/hip_bf16.h>

#define TK 20
#define BN 65536

typedef const float* fpc;

// ---------------- K1: top-20 cosine graph + emi/emj + u_i/u_j + lin_w transpose + zero bnsum ----------------
__global__ void k_graph(fpc emb, fpc att_em_i, fpc att_em_j, fpc lin_w, fpc att_i, fpc att_j,
                        int* __restrict__ topk, float* __restrict__ emi, float* __restrict__ emj,
                        float* __restrict__ u_i, float* __restrict__ u_j,
                        float* __restrict__ lwT, float* __restrict__ bnsum){
  const int t = threadIdx.x;
  if (blockIdx.x == 256){
    if (t < 64){
      float s = 0.f;
      for (int c = 0; c < 64; ++c) s = fmaf(lin_w[t*64 + c], att_i[c], s);
      u_i[t] = s;
    } else if (t < 128){
      const int f = t - 64;
      float s = 0.f;
      for (int c = 0; c < 64; ++c) s = fmaf(lin_w[f*64 + c], att_j[c], s);
      u_j[f] = s;
    }
    for (int i = t; i < 4096; i += 256) lwT[(i & 63)*64 + (i >> 6)] = lin_w[i];
    for (int i = t; i < 2048; i += 256) bnsum[i] = 0.f;
    return;
  }
  __shared__ float s_cos[256];
  __shared__ float s_wi[64];
  const int i = blockIdx.x;
  if (t < 64) s_wi[t] = emb[i*64 + t];
  __syncthreads();
  float dot = 0.f, nj = 0.f, ni = 0.f;
  for (int f = 0; f < 64; ++f){
    float wj = emb[t*64 + f], wi = s_wi[f];
    dot = fmaf(wi, wj, dot); nj = fmaf(wj, wj, nj); ni = fmaf(wi, wi, ni);
  }
  s_cos[t] = dot / (sqrtf(ni) * sqrtf(nj));
  __syncthreads();

  if (t < 64){
    // wave 0: 20 rounds of argmax (tie -> lower index) over 256 values
    float v0 = s_cos[t], v1 = s_cos[t+64], v2 = s_cos[t+128], v3 = s_cos[t+192];
    int taken = 0;
    for (int r = 0; r < TK; ++r){
      float bv = (taken & 1) ? -3.f : v0; int bi = t;
      float c;
      c = (taken & 2) ? -3.f : v1; if (c > bv){ bv = c; bi = t+64;  }
      c = (taken & 4) ? -3.f : v2; if (c > bv){ bv = c; bi = t+128; }
      c = (taken & 8) ? -3.f : v3; if (c > bv){ bv = c; bi = t+192; }
      for (int m = 1; m < 64; m <<= 1){
        float ov = __shfl_xor(bv, m, 64);
        int   oi = __shfl_xor(bi, m, 64);
        if (ov > bv || (ov == bv && oi < bi)){ bv = ov; bi = oi; }
      }
      if (t == 0) topk[i*TK + r] = bi;
      if ((bi & 63) == t) taken |= 1 << (bi >> 6);
    }
  } else if (t < 128){
    int d = t - 64;
    float wv = s_wi[d];
    float p1 = wv * att_em_i[d];
    float p2 = wv * att_em_j[d];
    for (int m = 1; m < 64; m <<= 1){
      p1 += __shfl_xor(p1, m, 64);
      p2 += __shfl_xor(p2, m, 64);
    }
    if (d == 0){ emi[i] = p1; emj[i] = p2; }
  }
}

// ---------------- K2: xl = data @ lin_w (bf16) -- weights in 16 NAMED float4 regs (no array => no spill) ----------------
__global__ void __launch_bounds__(256, 4) k_xl(fpc data, const float* __restrict__ lwT,
                                               __hip_bfloat16* __restrict__ xl){
  const int t = threadIdx.x, w = t >> 6, lane = t & 63;
  const float4* wt = (const float4*)(lwT + lane*64);   // lane's weight column, contiguous
  float4 W0=wt[0], W1=wt[1], W2=wt[2], W3=wt[3], W4=wt[4], W5=wt[5], W6=wt[6], W7=wt[7],
         W8=wt[8], W9=wt[9], W10=wt[10], W11=wt[11], W12=wt[12], W13=wt[13], W14=wt[14], W15=wt[15];
  const int rbase = blockIdx.x*64 + w*16;              // 1024 blocks x 64 rows; 16 rows/wave
  #pragma unroll 4
  for (int j = 0; j < 16; ++j){
    const int r = rbase + j;
    const float4* xp = (const float4*)(data + (size_t)r*64);
    float a0 = 0.f, a1 = 0.f, a2 = 0.f, a3 = 0.f;
#define FM(K) { float4 xq = xp[K]; a0 = fmaf(xq.x, W##K.x, a0); a1 = fmaf(xq.y, W##K.y, a1); \
                a2 = fmaf(xq.z, W##K.z, a2); a3 = fmaf(xq.w, W##K.w, a3); }
    FM(0) FM(1) FM(2) FM(3) FM(4) FM(5) FM(6) FM(7)
    FM(8) FM(9) FM(10) FM(11) FM(12) FM(13) FM(14) FM(15)
#undef FM
    xl[(size_t)r*64 + lane] = __float2bfloat16((a0 + a1) + (a2 + a3));
  }
}

// ---------------- K2b: aip/ajp -- quad-per-row, coalesced, width-4 reduce ----------------
__global__ void __launch_bounds__(256) k_scal(fpc data, const float* __restrict__ u_i,
                       const float* __restrict__ u_j, fpc emi, fpc emj,
                       float* __restrict__ aip, float* __restrict__ ajp){
  __shared__ float4 s_ui[16], s_uj[16];
  const int t = threadIdx.x;
  if (t < 16)      s_ui[t]      = ((const float4*)u_i)[t];
  else if (t < 32) s_uj[t - 16] = ((const float4*)u_j)[t - 16];
  __syncthreads();
  const int g = blockIdx.x*256 + t;          // 1024 blocks: g in [0, 262144)
  const int r = g >> 2, q = g & 3;           // 4 lanes per row, coalesced
  const float4* d4 = (const float4*)data + (size_t)r*16 + q*4;
  float p1 = 0.f, p2 = 0.f;
  #pragma unroll
  for (int i = 0; i < 4; ++i){
    float4 d = d4[i];
    float4 ui = s_ui[q*4 + i], uj = s_uj[q*4 + i];
    p1 = fmaf(d.x, ui.x, fmaf(d.y, ui.y, fmaf(d.z, ui.z, fmaf(d.w, ui.w, p1))));
    p2 = fmaf(d.x, uj.x, fmaf(d.y, uj.y, fmaf(d.z, uj.z, fmaf(d.w, uj.w, p2))));
  }
  p1 += __shfl_xor(p1, 1, 64); p1 += __shfl_xor(p1, 2, 64);
  p2 += __shfl_xor(p2, 1, 64); p2 += __shfl_xor(p2, 2, 64);
  if (q == 0)      aip[r] = p1 + emi[r & 255];
  else if (q == 1) ajp[r] = p2 + emj[r & 255];
}

// ---------------- K3: edge softmax + gather aggregation + bn1 shadow stats (16 nodes/wave) ----------------
__global__ void __launch_bounds__(256) k_attn_agg(const int* __restrict__ topk,
                         const __hip_bfloat16* __restrict__ xl,
                         fpc aip, fpc ajp, fpc gnn_bias, float* __restrict__ agg,
                         float* __restrict__ bnsum){
  __shared__ float s_alpha[4][32];
  __shared__ int   s_src[4][32];
  __shared__ float s_ps[4][64], s_pq[4][64];
  const int t = threadIdx.x, w = t >> 6, lane = t & 63;
  const float bias = gnn_bias[lane];
  const int vbase = blockIdx.x*64 + w*16;    // 1024 blocks x 64 nodes; 16/wave
  float sum = 0.f, sq = 0.f;
  for (int j = 0; j < 16; ++j){
    const int v = vbase + j, i = v & 255, b = v >> 8;
    float lg = -1e30f; int sl = 0;
    if (lane < 21){
      sl = (lane < 20) ? topk[i*TK + lane] : i;
      if (lane == 20 || sl != i){            // remove_self_loops, keep appended loop
        float l = aip[v] + ajp[b*256 + sl];
        lg = (l >= 0.f) ? l : 0.2f*l;        // leaky_relu(0.2)
      }
    }
    float m = lg;
    for (int s = 1; s < 32; s <<= 1) m = fmaxf(m, __shfl_xor(m, s, 32));
    float e = (lg > -1e29f) ? __expf(lg - m) : 0.f;
    float den = e;
    for (int s = 1; s < 32; s <<= 1) den += __shfl_xor(den, s, 32);
    if (lane < 21){ s_alpha[w][lane] = e / den; s_src[w][lane] = b*256 + sl; }
    // same-wave LDS RAW: in-order per wave
    float acc = bias;
    #pragma unroll
    for (int k = 0; k < 21; ++k)
      acc = fmaf(s_alpha[w][k], __bfloat162float(xl[(size_t)s_src[w][k]*64 + lane]), acc);
    agg[(size_t)v*64 + lane] = acc;
    sum += acc; sq = fmaf(acc, acc, sq);
  }
  s_ps[w][lane] = sum; s_pq[w][lane] = sq;
  __syncthreads();
  if (t < 64){
    const int cp = (blockIdx.x & 7)*64;
    atomicAdd(&bnsum[cp + t],       s_ps[0][t] + s_ps[1][t] + s_ps[2][t] + s_ps[3][t]);
    atomicAdd(&bnsum[512 + cp + t], s_pq[0][t] + s_pq[1][t] + s_pq[2][t] + s_pq[3][t]);
  }
}

// ---------------- K4: bn1 finalize + ReLU in place (float4) + bn2 shadow stats ----------------
__global__ void __launch_bounds__(256) k_bn1_apply(float* __restrict__ agg, fpc emb, fpc g1, fpc be1,
                          float* __restrict__ bnsum){
  const int t = threadIdx.x, qc = t & 15, rs = t >> 4;
  float4 sc, sh;
  {
    float s[4], q[4];
    #pragma unroll
    for (int k = 0; k < 4; ++k){
      const int d = qc*4 + k;
      float S = 0.f, Q = 0.f;
      #pragma unroll
      for (int cp = 0; cp < 8; ++cp){ S += bnsum[cp*64 + d]; Q += bnsum[512 + cp*64 + d]; }
      float mean = S * (1.f/BN);
      float var  = Q * (1.f/BN) - mean*mean;
      s[k] = g1[d] * rsqrtf(var + 1e-5f);
      q[k] = be1[d] - mean*s[k];
    }
    sc = make_float4(s[0], s[1], s[2], s[3]);
    sh = make_float4(q[0], q[1], q[2], q[3]);
  }
  float4* agg4 = (float4*)agg;
  const float4* emb4 = (const float4*)emb;
  float4 ys = make_float4(0,0,0,0), yq = make_float4(0,0,0,0);
  const int rbase = blockIdx.x*32;           // 2048 blocks x 32 rows
  #pragma unroll
  for (int jj = 0; jj < 2; ++jj){
    const int r = rbase + jj*16 + rs;
    float4 x = agg4[(size_t)r*16 + qc];
    float4 g;
    g.x = fmaxf(fmaf(x.x, sc.x, sh.x), 0.f);
    g.y = fmaxf(fmaf(x.y, sc.y, sh.y), 0.f);
    g.z = fmaxf(fmaf(x.z, sc.z, sh.z), 0.f);
    g.w = fmaxf(fmaf(x.w, sc.w, sh.w), 0.f);
    agg4[(size_t)r*16 + qc] = g;             // gnn_out in place
    float4 e = emb4[(r & 255)*16 + qc];
    float4 y = make_float4(g.x*e.x, g.y*e.y, g.z*e.z, g.w*e.w);
    ys.x += y.x; ys.y += y.y; ys.z += y.z; ys.w += y.w;
    yq.x = fmaf(y.x, y.x, yq.x); yq.y = fmaf(y.y, y.y, yq.y);
    yq.z = fmaf(y.z, y.z, yq.z); yq.w = fmaf(y.w, y.w, yq.w);
  }
  __shared__ float4 s_s[16][16], s_q[16][16];
  s_s[rs][qc] = ys; s_q[rs][qc] = yq;
  __syncthreads();
  if (t < 64){
    const int qq = t >> 2, comp = t & 3;
    float S = 0.f, Q = 0.f;
    #pragma unroll
    for (int rr = 0; rr < 16; ++rr){
      S += ((const float*)&s_s[rr][qq])[comp];
      Q += ((const float*)&s_q[rr][qq])[comp];
    }
    const int cp = (blockIdx.x & 7)*64;
    atomicAdd(&bnsum[1024 + cp + t], S);
    atomicAdd(&bnsum[1536 + cp + t], Q);
  }
}

// ---------------- K5: split-K encoder GEMM -> partials, grid (64 kt, 16 bt) ----------------
__global__ void __launch_bounds__(256) k_enc(const float* __restrict__ gnn, fpc enc_w,
                                             float* __restrict__ part){
  __shared__ float s_g[16][256];             // 16 KB
  const int t = threadIdx.x;
  const int kt = blockIdx.x, bt = blockIdx.y;
  const int kbase = kt*256;
  #pragma unroll
  for (int i = 0; i < 16; ++i)
    s_g[i][t] = gnn[(size_t)(bt*16 + i)*16384 + kbase + t];
  __syncthreads();
  const int w = t >> 6, c = t & 63, r0 = w*4;
  float a0=0.f, a1=0.f, a2=0.f, a3=0.f;
  for (int k = 0; k < 256; k += 4){
    float e0 = enc_w[(size_t)(kbase + k + 0)*64 + c];
    float e1 = enc_w[(size_t)(kbase + k + 1)*64 + c];
    float e2 = enc_w[(size_t)(kbase + k + 2)*64 + c];
    float e3 = enc_w[(size_t)(kbase + k + 3)*64 + c];
    float4 g0 = *(const float4*)&s_g[r0 + 0][k];
    float4 g1 = *(const float4*)&s_g[r0 + 1][k];
    float4 g2 = *(const float4*)&s_g[r0 + 2][k];
    float4 g3 = *(const float4*)&s_g[r0 + 3][k];
    a0 = fmaf(g0.x, e0, fmaf(g0.y, e1, fmaf(g0.z, e2, fmaf(g0.w, e3, a0))));
    a1 = fmaf(g1.x, e0, fmaf(g1.y, e1, fmaf(g1.z, e2, fmaf(g1.w, e3, a1))));
    a2 = fmaf(g2.x, e0, fmaf(g2.y, e1, fmaf(g2.z, e2, fmaf(g2.w, e3, a2))));
    a3 = fmaf(g3.x, e0, fmaf(g3.y, e1, fmaf(g3.z, e2, fmaf(g3.w, e3, a3))));
  }
  part[(size_t)kt*16384 + (bt*16 + r0 + 0)*64 + c] = a0;
  part[(size_t)kt*16384 + (bt*16 + r0 + 1)*64 + c] = a1;
  part[(size_t)kt*16384 + (bt*16 + r0 + 2)*64 + c] = a2;
  part[(size_t)kt*16384 + (bt*16 + r0 + 3)*64 + c] = a3;
}

// ---------------- K5b: reduce split-K partials -> encoded ----------------
__global__ void __launch_bounds__(256) k_red(const float* __restrict__ part,
                                             float* __restrict__ encoded){
  const int idx = blockIdx.x*256 + threadIdx.x;   // 64 blocks x 256 = 16384
  float s = 0.f;
  #pragma unroll 8
  for (int kt = 0; kt < 64; ++kt) s += part[(size_t)kt*16384 + idx];
  encoded[idx] = s;
}

// ---------------- K6: score head (float4, width-16 reduce) + arrangement in block 0 ----------------
__global__ void __launch_bounds__(256) k_score(const float* __restrict__ gnn, fpc emb, fpc g2, fpc be2,
                      const float* __restrict__ bnsum, fpc out_w, fpc out_b,
                      const float* __restrict__ encoded, fpc enc_b, fpc arr_w, fpc arr_b,
                      float* __restrict__ out){
  const int t = threadIdx.x, w = t >> 6, lane = t & 63;
  const int qc = lane & 15, rq = lane >> 4;
  float sc2[4], sh2[4], ow[4];
  #pragma unroll
  for (int k = 0; k < 4; ++k){
    const int d = qc*4 + k;
    float S = 0.f, Q = 0.f;
    #pragma unroll
    for (int cp = 0; cp < 8; ++cp){ S += bnsum[1024 + cp*64 + d]; Q += bnsum[1536 + cp*64 + d]; }
    float mean = S * (1.f/BN);
    float var  = Q * (1.f/BN) - mean*mean;
    sc2[k] = g2[d] * rsqrtf(var + 1e-5f);
    sh2[k] = be2[d] - mean*sc2[k];
    ow[k]  = out_w[d];
  }
  const float ob = out_b[0];
  const float4* gnn4 = (const float4*)gnn;
  const float4* emb4 = (const float4*)emb;
  const int base = blockIdx.x*32 + w*8;      // 2048 blocks x 32 rows
  #pragma unroll
  for (int it = 0; it < 2; ++it){
    const int r = base + it*4 + rq;
    float4 y4 = gnn4[(size_t)r*16 + qc];
    float4 e4 = emb4[(r & 255)*16 + qc];
    float p = 0.f, yh;
    yh = fmaxf(fmaf(y4.x*e4.x, sc2[0], sh2[0]), 0.f); p = fmaf(yh, ow[0], p);
    yh = fmaxf(fmaf(y4.y*e4.y, sc2[1], sh2[1]), 0.f); p = fmaf(yh, ow[1], p);
    yh = fmaxf(fmaf(y4.z*e4.z, sc2[2], sh2[2]), 0.f); p = fmaf(yh, ow[2], p);
    yh = fmaxf(fmaf(y4.w*e4.w, sc2[3], sh2[3]), 0.f); p = fmaf(yh, ow[3], p);
    #pragma unroll
    for (int m = 1; m < 16; m <<= 1) p += __shfl_xor(p, m, 16);
    if (qc == 0) out[r] = p + ob;
  }
  if (blockIdx.x == 0){
    const int b = t;
    float o[7];
    #pragma unroll
    for (int j = 0; j < 7; ++j) o[j] = arr_b[j];
    for (int c = 0; c < 64; ++c){
      float e = encoded[b*64 + c] + enc_b[c];
      #pragma unroll
      for (int j = 0; j < 7; ++j) o[j] = fmaf(e, arr_w[c*7 + j], o[j]);
    }
    #pragma unroll
    for (int j = 0; j < 7; ++j) out[65536 + b*7 + j] = o[j];
  }
}

extern "C" void kernel_launch(void* const* d_in, const int* in_sizes, int n_in,
                              void* d_out, int out_size, void* d_ws, size_t ws_size,
                              hipStream_t stream) {
  fpc data     = (fpc)d_in[0];
  fpc emb      = (fpc)d_in[1];
  fpc lin_w    = (fpc)d_in[2];
  fpc att_i    = (fpc)d_in[3];
  fpc att_j    = (fpc)d_in[4];
  fpc att_em_i = (fpc)d_in[5];
  fpc att_em_j = (fpc)d_in[6];
  fpc gnn_bias = (fpc)d_in[7];
  fpc g1       = (fpc)d_in[8];
  fpc be1      = (fpc)d_in[9];
  fpc g2       = (fpc)d_in[10];
  fpc be2      = (fpc)d_in[11];
  fpc enc_w    = (fpc)d_in[12];
  fpc enc_b    = (fpc)d_in[13];
  fpc arr_w    = (fpc)d_in[14];
  fpc arr_b    = (fpc)d_in[15];
  fpc out_w    = (fpc)d_in[16];
  fpc out_b    = (fpc)d_in[17];

  float* fw = (float*)d_ws;
  int*   topk    = (int*)d_ws;            // [0, 5120)
  float* emi     = fw + 5120;             // 256
  float* emj     = fw + 5376;             // 256
  float* u_i     = fw + 5632;             // 64
  float* u_j     = fw + 5696;             // 64
  float* lwT     = fw + 5760;             // 4096 (transposed lin_w)
  float* bnsum   = fw + 9856;             // 2048 shadow BN accumulators (zeroed in k_graph)
  float* encoded = fw + 11904;            // 16384
  float* aip     = fw + 28288;            // 65536
  float* ajp     = fw + 93824;            // 65536
  float* agg     = fw + 159360;           // 65536*64 f32 (becomes gnn_out in place)
  __hip_bfloat16* xl = (__hip_bfloat16*)(fw + 4353664);  // 65536*64 bf16 = 8.4 MB
  float* part    = (float*)xl;            // 64*16384 f32 = 4 MB, aliases dead xl (order-separated)
  float* out     = (float*)d_out;

  k_graph    <<<257,   256, 0, stream>>>(emb, att_em_i, att_em_j, lin_w, att_i, att_j,
                                         topk, emi, emj, u_i, u_j, lwT, bnsum);
  k_xl       <<<1024,  256, 0, stream>>>(data, lwT, xl);
  k_scal     <<<1024,  256, 0, stream>>>(data, u_i, u_j, emi, emj, aip, ajp);
  k_attn_agg <<<1024,  256, 0, stream>>>(topk, xl, aip, ajp, gnn_bias, agg, bnsum);
  k_bn1_apply<<<2048,  256, 0, stream>>>(agg, emb, g1, be1, bnsum);
  k_enc      <<<dim3(64,16), 256, 0, stream>>>(agg, enc_w, part);
  k_red      <<<64,    256, 0, stream>>>(part, encoded);
  k_score    <<<2048,  256, 0, stream>>>(agg, emb, g2, be2, bnsum, out_w, out_b,
                                         encoded, enc_b, arr_w, arr_b, out);
}

// Round 9
// 223.170 us; speedup vs baseline: 1.6135x; 1.6135x over previous
//
#include <hip/hip_runtime.h>
#include <hip/hip_bf16.h>

#define TK 20
#define BN 65536

typedef const float* fpc;

// ---------------- K1: top-20 cosine graph + emi/emj ----------------
__global__ void k_graph(fpc emb, fpc att_em_i, fpc att_em_j,
                        int* __restrict__ topk, float* __restrict__ emi, float* __restrict__ emj){
  __shared__ float s_cos[256];
  __shared__ float s_wi[64];
  const int i = blockIdx.x;
  const int t = threadIdx.x;
  if (t < 64) s_wi[t] = emb[i*64 + t];
  __syncthreads();
  float dot = 0.f, nj = 0.f, ni = 0.f;
  for (int f = 0; f < 64; ++f){
    float wj = emb[t*64 + f], wi = s_wi[f];
    dot = fmaf(wi, wj, dot); nj = fmaf(wj, wj, nj); ni = fmaf(wi, wi, ni);
  }
  s_cos[t] = dot / (sqrtf(ni) * sqrtf(nj));
  __syncthreads();

  if (t < 64){
    // wave 0: 20 rounds of argmax (tie -> lower index) over 256 values
    float v0 = s_cos[t], v1 = s_cos[t+64], v2 = s_cos[t+128], v3 = s_cos[t+192];
    int taken = 0;
    for (int r = 0; r < TK; ++r){
      float bv = (taken & 1) ? -3.f : v0; int bi = t;
      float c;
      c = (taken & 2) ? -3.f : v1; if (c > bv){ bv = c; bi = t+64;  }
      c = (taken & 4) ? -3.f : v2; if (c > bv){ bv = c; bi = t+128; }
      c = (taken & 8) ? -3.f : v3; if (c > bv){ bv = c; bi = t+192; }
      for (int m = 1; m < 64; m <<= 1){
        float ov = __shfl_xor(bv, m, 64);
        int   oi = __shfl_xor(bi, m, 64);
        if (ov > bv || (ov == bv && oi < bi)){ bv = ov; bi = oi; }
      }
      if (t == 0) topk[i*TK + r] = bi;
      if ((bi & 63) == t) taken |= 1 << (bi >> 6);
    }
  } else if (t < 128){
    int d = t - 64;
    float wv = s_wi[d];
    float p1 = wv * att_em_i[d];
    float p2 = wv * att_em_j[d];
    for (int m = 1; m < 64; m <<= 1){
      p1 += __shfl_xor(p1, m, 64);
      p2 += __shfl_xor(p2, m, 64);
    }
    if (d == 0){ emi[i] = p1; emj[i] = p2; }
  }
}

// ---------------- K2: xl = data @ lin_w (bf16) + aip/ajp; K split across 4 waves ----------------
// Wave w owns f in [16w, 16w+16): only 16 weight VGPRs/lane (no 64-reg array => no spill).
// Partials through LDS part[w][j][c] (bank c%32: 2-way, free). Phase B sums 4 partials,
// emits bf16 xl + shuffle-reduced aip/ajp (replaces k_scal entirely).
__global__ void __launch_bounds__(256) k_xl(fpc data, fpc lin_w, fpc att_i, fpc att_j,
                     fpc emi, fpc emj,
                     __hip_bfloat16* __restrict__ xl,
                     float* __restrict__ aip, float* __restrict__ ajp){
  __shared__ float part[4][32][64];          // 32 KB
  const int t = threadIdx.x, w = t >> 6, lane = t & 63;
  float W[16];
  #pragma unroll
  for (int k = 0; k < 16; ++k) W[k] = lin_w[(w*16 + k)*64 + lane];  // coalesced
  const int rbase = blockIdx.x*32;           // 2048 blocks x 32 rows
  // phase A: per-wave K-slice partials
  for (int j = 0; j < 32; ++j){
    const float4* xp = (const float4*)(data + (size_t)(rbase + j)*64 + w*16);
    float4 x0 = xp[0], x1 = xp[1], x2 = xp[2], x3 = xp[3];   // wave-uniform broadcast
    float a0 = 0.f, a1 = 0.f, a2 = 0.f, a3 = 0.f;
    a0 = fmaf(x0.x, W[0],  a0); a1 = fmaf(x0.y, W[1],  a1);
    a2 = fmaf(x0.z, W[2],  a2); a3 = fmaf(x0.w, W[3],  a3);
    a0 = fmaf(x1.x, W[4],  a0); a1 = fmaf(x1.y, W[5],  a1);
    a2 = fmaf(x1.z, W[6],  a2); a3 = fmaf(x1.w, W[7],  a3);
    a0 = fmaf(x2.x, W[8],  a0); a1 = fmaf(x2.y, W[9],  a1);
    a2 = fmaf(x2.z, W[10], a2); a3 = fmaf(x2.w, W[11], a3);
    a0 = fmaf(x3.x, W[12], a0); a1 = fmaf(x3.y, W[13], a1);
    a2 = fmaf(x3.z, W[14], a2); a3 = fmaf(x3.w, W[15], a3);
    part[w][j][lane] = (a0 + a1) + (a2 + a3);
  }
  __syncthreads();
  // phase B: wave w handles rows j = i*4 + w; lanes = columns
  const float ati = att_i[lane], atj = att_j[lane];
  #pragma unroll
  for (int i = 0; i < 8; ++i){
    const int j = i*4 + w;
    const int r = rbase + j;
    float s = part[0][j][lane] + part[1][j][lane] + part[2][j][lane] + part[3][j][lane];
    xl[(size_t)r*64 + lane] = __float2bfloat16(s);
    float p1 = s*ati, p2 = s*atj;
    #pragma unroll
    for (int m = 1; m < 64; m <<= 1){
      p1 += __shfl_xor(p1, m, 64);
      p2 += __shfl_xor(p2, m, 64);
    }
    if (lane == 0){
      const int node = r & 255;
      aip[r] = p1 + emi[node];
      ajp[r] = p2 + emj[node];
    }
  }
}

// ---------------- K3: edge softmax + gather aggregation + bn1 shadow stats (16 nodes/wave) ----------------
__global__ void __launch_bounds__(256) k_attn_agg(const int* __restrict__ topk,
                         const __hip_bfloat16* __restrict__ xl,
                         fpc aip, fpc ajp, fpc gnn_bias, float* __restrict__ agg,
                         float* __restrict__ bnsum){
  __shared__ float s_alpha[4][32];
  __shared__ int   s_src[4][32];
  __shared__ float s_ps[4][64], s_pq[4][64];
  const int t = threadIdx.x, w = t >> 6, lane = t & 63;
  const float bias = gnn_bias[lane];
  const int vbase = blockIdx.x*64 + w*16;    // 1024 blocks x 64 nodes; 16/wave
  float sum = 0.f, sq = 0.f;
  for (int j = 0; j < 16; ++j){
    const int v = vbase + j, i = v & 255, b = v >> 8;
    float lg = -1e30f; int sl = 0;
    if (lane < 21){
      sl = (lane < 20) ? topk[i*TK + lane] : i;
      if (lane == 20 || sl != i){            // remove_self_loops, keep appended loop
        float l = aip[v] + ajp[b*256 + sl];
        lg = (l >= 0.f) ? l : 0.2f*l;        // leaky_relu(0.2)
      }
    }
    float m = lg;
    for (int s = 1; s < 32; s <<= 1) m = fmaxf(m, __shfl_xor(m, s, 32));
    float e = (lg > -1e29f) ? __expf(lg - m) : 0.f;
    float den = e;
    for (int s = 1; s < 32; s <<= 1) den += __shfl_xor(den, s, 32);
    if (lane < 21){ s_alpha[w][lane] = e / den; s_src[w][lane] = b*256 + sl; }
    // same-wave LDS RAW: in-order per wave
    float acc = bias;
    #pragma unroll
    for (int k = 0; k < 21; ++k)
      acc = fmaf(s_alpha[w][k], __bfloat162float(xl[(size_t)s_src[w][k]*64 + lane]), acc);
    agg[(size_t)v*64 + lane] = acc;
    sum += acc; sq = fmaf(acc, acc, sq);
  }
  s_ps[w][lane] = sum; s_pq[w][lane] = sq;
  __syncthreads();
  if (t < 64){
    const int cp = (blockIdx.x & 7)*64;
    atomicAdd(&bnsum[cp + t],       s_ps[0][t] + s_ps[1][t] + s_ps[2][t] + s_ps[3][t]);
    atomicAdd(&bnsum[512 + cp + t], s_pq[0][t] + s_pq[1][t] + s_pq[2][t] + s_pq[3][t]);
  }
}

// ---------------- K4: bn1 finalize + ReLU in place (float4) + bn2 shadow stats ----------------
__global__ void __launch_bounds__(256) k_bn1_apply(float* __restrict__ agg, fpc emb, fpc g1, fpc be1,
                          float* __restrict__ bnsum){
  const int t = threadIdx.x, qc = t & 15, rs = t >> 4;
  float4 sc, sh;
  {
    float s[4], q[4];
    #pragma unroll
    for (int k = 0; k < 4; ++k){
      const int d = qc*4 + k;
      float S = 0.f, Q = 0.f;
      #pragma unroll
      for (int cp = 0; cp < 8; ++cp){ S += bnsum[cp*64 + d]; Q += bnsum[512 + cp*64 + d]; }
      float mean = S * (1.f/BN);
      float var  = Q * (1.f/BN) - mean*mean;
      s[k] = g1[d] * rsqrtf(var + 1e-5f);
      q[k] = be1[d] - mean*s[k];
    }
    sc = make_float4(s[0], s[1], s[2], s[3]);
    sh = make_float4(q[0], q[1], q[2], q[3]);
  }
  float4* agg4 = (float4*)agg;
  const float4* emb4 = (const float4*)emb;
  float4 ys = make_float4(0,0,0,0), yq = make_float4(0,0,0,0);
  const int rbase = blockIdx.x*32;           // 2048 blocks x 32 rows
  #pragma unroll
  for (int jj = 0; jj < 2; ++jj){
    const int r = rbase + jj*16 + rs;
    float4 x = agg4[(size_t)r*16 + qc];
    float4 g;
    g.x = fmaxf(fmaf(x.x, sc.x, sh.x), 0.f);
    g.y = fmaxf(fmaf(x.y, sc.y, sh.y), 0.f);
    g.z = fmaxf(fmaf(x.z, sc.z, sh.z), 0.f);
    g.w = fmaxf(fmaf(x.w, sc.w, sh.w), 0.f);
    agg4[(size_t)r*16 + qc] = g;             // gnn_out in place
    float4 e = emb4[(r & 255)*16 + qc];
    float4 y = make_float4(g.x*e.x, g.y*e.y, g.z*e.z, g.w*e.w);
    ys.x += y.x; ys.y += y.y; ys.z += y.z; ys.w += y.w;
    yq.x = fmaf(y.x, y.x, yq.x); yq.y = fmaf(y.y, y.y, yq.y);
    yq.z = fmaf(y.z, y.z, yq.z); yq.w = fmaf(y.w, y.w, yq.w);
  }
  __shared__ float4 s_s[16][16], s_q[16][16];
  s_s[rs][qc] = ys; s_q[rs][qc] = yq;
  __syncthreads();
  if (t < 64){
    const int qq = t >> 2, comp = t & 3;
    float S = 0.f, Q = 0.f;
    #pragma unroll
    for (int rr = 0; rr < 16; ++rr){
      S += ((const float*)&s_s[rr][qq])[comp];
      Q += ((const float*)&s_q[rr][qq])[comp];
    }
    const int cp = (blockIdx.x & 7)*64;
    atomicAdd(&bnsum[1024 + cp + t], S);
    atomicAdd(&bnsum[1536 + cp + t], Q);
  }
}

// ---------------- K5: split-K encoder GEMM -> partials, grid (64 kt, 16 bt) ----------------
__global__ void __launch_bounds__(256) k_enc(const float* __restrict__ gnn, fpc enc_w,
                                             float* __restrict__ part){
  __shared__ float s_g[16][256];             // 16 KB
  const int t = threadIdx.x;
  const int kt = blockIdx.x, bt = blockIdx.y;
  const int kbase = kt*256;
  #pragma unroll
  for (int i = 0; i < 16; ++i)
    s_g[i][t] = gnn[(size_t)(bt*16 + i)*16384 + kbase + t];
  __syncthreads();
  const int w = t >> 6, c = t & 63, r0 = w*4;
  float a0=0.f, a1=0.f, a2=0.f, a3=0.f;
  for (int k = 0; k < 256; k += 4){
    float e0 = enc_w[(size_t)(kbase + k + 0)*64 + c];
    float e1 = enc_w[(size_t)(kbase + k + 1)*64 + c];
    float e2 = enc_w[(size_t)(kbase + k + 2)*64 + c];
    float e3 = enc_w[(size_t)(kbase + k + 3)*64 + c];
    float4 g0 = *(const float4*)&s_g[r0 + 0][k];
    float4 g1 = *(const float4*)&s_g[r0 + 1][k];
    float4 g2 = *(const float4*)&s_g[r0 + 2][k];
    float4 g3 = *(const float4*)&s_g[r0 + 3][k];
    a0 = fmaf(g0.x, e0, fmaf(g0.y, e1, fmaf(g0.z, e2, fmaf(g0.w, e3, a0))));
    a1 = fmaf(g1.x, e0, fmaf(g1.y, e1, fmaf(g1.z, e2, fmaf(g1.w, e3, a1))));
    a2 = fmaf(g2.x, e0, fmaf(g2.y, e1, fmaf(g2.z, e2, fmaf(g2.w, e3, a2))));
    a3 = fmaf(g3.x, e0, fmaf(g3.y, e1, fmaf(g3.z, e2, fmaf(g3.w, e3, a3))));
  }
  part[(size_t)kt*16384 + (bt*16 + r0 + 0)*64 + c] = a0;
  part[(size_t)kt*16384 + (bt*16 + r0 + 1)*64 + c] = a1;
  part[(size_t)kt*16384 + (bt*16 + r0 + 2)*64 + c] = a2;
  part[(size_t)kt*16384 + (bt*16 + r0 + 3)*64 + c] = a3;
}

// ---------------- K5b: reduce split-K partials -> encoded ----------------
__global__ void __launch_bounds__(256) k_red(const float* __restrict__ part,
                                             float* __restrict__ encoded){
  const int idx = blockIdx.x*256 + threadIdx.x;   // 64 blocks x 256 = 16384
  float s = 0.f;
  #pragma unroll 8
  for (int kt = 0; kt < 64; ++kt) s += part[(size_t)kt*16384 + idx];
  encoded[idx] = s;
}

// ---------------- K6: score head (float4, width-16 reduce) + arrangement in block 0 ----------------
__global__ void __launch_bounds__(256) k_score(const float* __restrict__ gnn, fpc emb, fpc g2, fpc be2,
                      const float* __restrict__ bnsum, fpc out_w, fpc out_b,
                      const float* __restrict__ encoded, fpc enc_b, fpc arr_w, fpc arr_b,
                      float* __restrict__ out){
  const int t = threadIdx.x, w = t >> 6, lane = t & 63;
  const int qc = lane & 15, rq = lane >> 4;
  float sc2[4], sh2[4], ow[4];
  #pragma unroll
  for (int k = 0; k < 4; ++k){
    const int d = qc*4 + k;
    float S = 0.f, Q = 0.f;
    #pragma unroll
    for (int cp = 0; cp < 8; ++cp){ S += bnsum[1024 + cp*64 + d]; Q += bnsum[1536 + cp*64 + d]; }
    float mean = S * (1.f/BN);
    float var  = Q * (1.f/BN) - mean*mean;
    sc2[k] = g2[d] * rsqrtf(var + 1e-5f);
    sh2[k] = be2[d] - mean*sc2[k];
    ow[k]  = out_w[d];
  }
  const float ob = out_b[0];
  const float4* gnn4 = (const float4*)gnn;
  const float4* emb4 = (const float4*)emb;
  const int base = blockIdx.x*32 + w*8;      // 2048 blocks x 32 rows
  #pragma unroll
  for (int it = 0; it < 2; ++it){
    const int r = base + it*4 + rq;
    float4 y4 = gnn4[(size_t)r*16 + qc];
    float4 e4 = emb4[(r & 255)*16 + qc];
    float p = 0.f, yh;
    yh = fmaxf(fmaf(y4.x*e4.x, sc2[0], sh2[0]), 0.f); p = fmaf(yh, ow[0], p);
    yh = fmaxf(fmaf(y4.y*e4.y, sc2[1], sh2[1]), 0.f); p = fmaf(yh, ow[1], p);
    yh = fmaxf(fmaf(y4.z*e4.z, sc2[2], sh2[2]), 0.f); p = fmaf(yh, ow[2], p);
    yh = fmaxf(fmaf(y4.w*e4.w, sc2[3], sh2[3]), 0.f); p = fmaf(yh, ow[3], p);
    #pragma unroll
    for (int m = 1; m < 16; m <<= 1) p += __shfl_xor(p, m, 16);
    if (qc == 0) out[r] = p + ob;
  }
  if (blockIdx.x == 0){
    const int b = t;
    float o[7];
    #pragma unroll
    for (int j = 0; j < 7; ++j) o[j] = arr_b[j];
    for (int c = 0; c < 64; ++c){
      float e = encoded[b*64 + c] + enc_b[c];
      #pragma unroll
      for (int j = 0; j < 7; ++j) o[j] = fmaf(e, arr_w[c*7 + j], o[j]);
    }
    #pragma unroll
    for (int j = 0; j < 7; ++j) out[65536 + b*7 + j] = o[j];
  }
}

extern "C" void kernel_launch(void* const* d_in, const int* in_sizes, int n_in,
                              void* d_out, int out_size, void* d_ws, size_t ws_size,
                              hipStream_t stream) {
  fpc data     = (fpc)d_in[0];
  fpc emb      = (fpc)d_in[1];
  fpc lin_w    = (fpc)d_in[2];
  fpc att_i    = (fpc)d_in[3];
  fpc att_j    = (fpc)d_in[4];
  fpc att_em_i = (fpc)d_in[5];
  fpc att_em_j = (fpc)d_in[6];
  fpc gnn_bias = (fpc)d_in[7];
  fpc g1       = (fpc)d_in[8];
  fpc be1      = (fpc)d_in[9];
  fpc g2       = (fpc)d_in[10];
  fpc be2      = (fpc)d_in[11];
  fpc enc_w    = (fpc)d_in[12];
  fpc enc_b    = (fpc)d_in[13];
  fpc arr_w    = (fpc)d_in[14];
  fpc arr_b    = (fpc)d_in[15];
  fpc out_w    = (fpc)d_in[16];
  fpc out_b    = (fpc)d_in[17];

  float* fw = (float*)d_ws;
  int*   topk    = (int*)d_ws;            // [0, 5120)
  float* emi     = fw + 5120;             // 256
  float* emj     = fw + 5376;             // 256
  float* bnsum   = fw + 5632;             // 2048 shadow BN accumulators (memset below)
  float* encoded = fw + 7680;             // 16384
  float* aip     = fw + 24064;            // 65536
  float* ajp     = fw + 89600;            // 65536
  float* agg     = fw + 155136;           // 65536*64 f32 (becomes gnn_out in place)
  __hip_bfloat16* xl = (__hip_bfloat16*)(fw + 4349440);  // 65536*64 bf16 = 8.4 MB
  float* part    = (float*)xl;            // 64*16384 f32 = 4 MB, aliases dead xl (order-separated)
  float* out     = (float*)d_out;

  hipMemsetAsync((void*)bnsum, 0, 2048u*sizeof(float), stream);

  k_graph    <<<256,   256, 0, stream>>>(emb, att_em_i, att_em_j, topk, emi, emj);
  k_xl       <<<2048,  256, 0, stream>>>(data, lin_w, att_i, att_j, emi, emj, xl, aip, ajp);
  k_attn_agg <<<1024,  256, 0, stream>>>(topk, xl, aip, ajp, gnn_bias, agg, bnsum);
  k_bn1_apply<<<2048,  256, 0, stream>>>(agg, emb, g1, be1, bnsum);
  k_enc      <<<dim3(64,16), 256, 0, stream>>>(agg, enc_w, part);
  k_red      <<<64,    256, 0, stream>>>(part, encoded);
  k_score    <<<2048,  256, 0, stream>>>(agg, emb, g2, be2, bnsum, out_w, out_b,
                                         encoded, enc_b, arr_w, arr_b, out);
}

// Round 10
// 190.372 us; speedup vs baseline: 1.8915x; 1.1723x over previous
//
#include <hip/hip_runtime.h>
#include <hip/hip_bf16.h>

#define TK 20
#define BN 65536

typedef const float* fpc;
typedef __attribute__((ext_vector_type(8))) short short8;
typedef __attribute__((ext_vector_type(4))) float floatx4;

// f32 -> bf16 bits, round-to-nearest-even
__device__ __forceinline__ short f2b(float f){
  unsigned u = __float_as_uint(f);
  return (short)((u + 0x7fffu + ((u >> 16) & 1u)) >> 16);
}

// ---------------- K1: top-20 cosine graph + emi/emj ----------------
__global__ void k_graph(fpc emb, fpc att_em_i, fpc att_em_j,
                        int* __restrict__ topk, float* __restrict__ emi, float* __restrict__ emj){
  __shared__ float s_cos[256];
  __shared__ float s_wi[64];
  const int i = blockIdx.x;
  const int t = threadIdx.x;
  if (t < 64) s_wi[t] = emb[i*64 + t];
  __syncthreads();
  float dot = 0.f, nj = 0.f, ni = 0.f;
  for (int f = 0; f < 64; ++f){
    float wj = emb[t*64 + f], wi = s_wi[f];
    dot = fmaf(wi, wj, dot); nj = fmaf(wj, wj, nj); ni = fmaf(wi, wi, ni);
  }
  s_cos[t] = dot / (sqrtf(ni) * sqrtf(nj));
  __syncthreads();

  if (t < 64){
    // wave 0: 20 rounds of argmax (tie -> lower index) over 256 values
    float v0 = s_cos[t], v1 = s_cos[t+64], v2 = s_cos[t+128], v3 = s_cos[t+192];
    int taken = 0;
    for (int r = 0; r < TK; ++r){
      float bv = (taken & 1) ? -3.f : v0; int bi = t;
      float c;
      c = (taken & 2) ? -3.f : v1; if (c > bv){ bv = c; bi = t+64;  }
      c = (taken & 4) ? -3.f : v2; if (c > bv){ bv = c; bi = t+128; }
      c = (taken & 8) ? -3.f : v3; if (c > bv){ bv = c; bi = t+192; }
      for (int m = 1; m < 64; m <<= 1){
        float ov = __shfl_xor(bv, m, 64);
        int   oi = __shfl_xor(bi, m, 64);
        if (ov > bv || (ov == bv && oi < bi)){ bv = ov; bi = oi; }
      }
      if (t == 0) topk[i*TK + r] = bi;
      if ((bi & 63) == t) taken |= 1 << (bi >> 6);
    }
  } else if (t < 128){
    int d = t - 64;
    float wv = s_wi[d];
    float p1 = wv * att_em_i[d];
    float p2 = wv * att_em_j[d];
    for (int m = 1; m < 64; m <<= 1){
      p1 += __shfl_xor(p1, m, 64);
      p2 += __shfl_xor(p2, m, 64);
    }
    if (d == 0){ emi[i] = p1; emj[i] = p2; }
  }
}

// ---------------- K2: xl = data @ lin_w via MFMA 16x16x32 bf16 + aip/ajp ----------------
// A[m=lane&15][k=quad*8+j]; B[k=quad*8+j][n=lane&15]; D col=lane&15, row=quad*4+reg.
__global__ void __launch_bounds__(256) k_xl(fpc data, fpc lin_w, fpc att_i, fpc att_j,
                     fpc emi, fpc emj,
                     __hip_bfloat16* __restrict__ xl,
                     float* __restrict__ aip, float* __restrict__ ajp){
  const int t = threadIdx.x, w = t >> 6, lane = t & 63;
  const int m = lane & 15, quad = lane >> 4;
  // B fragments: lin_w[64 f][64 c], 4 col-tiles x 2 k-chunks
  short8 B[4][2];
  #pragma unroll
  for (int ct = 0; ct < 4; ++ct)
    #pragma unroll
    for (int kc = 0; kc < 2; ++kc)
      #pragma unroll
      for (int j = 0; j < 8; ++j)
        B[ct][kc][j] = f2b(lin_w[(kc*32 + quad*8 + j)*64 + ct*16 + m]);

  const int rw = blockIdx.x*64 + w*16;       // 1024 blocks x 64 rows; wave = 16-row tile
  // A fragments (2 k-chunks)
  short8 A0, A1;
  {
    const float4* ap0 = (const float4*)(data + (size_t)(rw + m)*64 + quad*8);
    float4 q0 = ap0[0], q1 = ap0[1];
    A0[0]=f2b(q0.x); A0[1]=f2b(q0.y); A0[2]=f2b(q0.z); A0[3]=f2b(q0.w);
    A0[4]=f2b(q1.x); A0[5]=f2b(q1.y); A0[6]=f2b(q1.z); A0[7]=f2b(q1.w);
    const float4* ap1 = (const float4*)(data + (size_t)(rw + m)*64 + 32 + quad*8);
    float4 q2 = ap1[0], q3 = ap1[1];
    A1[0]=f2b(q2.x); A1[1]=f2b(q2.y); A1[2]=f2b(q2.z); A1[3]=f2b(q2.w);
    A1[4]=f2b(q3.x); A1[5]=f2b(q3.y); A1[6]=f2b(q3.z); A1[7]=f2b(q3.w);
  }
  floatx4 acc[4];
  #pragma unroll
  for (int ct = 0; ct < 4; ++ct){
    floatx4 z = {0.f, 0.f, 0.f, 0.f};
    acc[ct] = __builtin_amdgcn_mfma_f32_16x16x32_bf16(A0, B[ct][0], z, 0, 0, 0);
    acc[ct] = __builtin_amdgcn_mfma_f32_16x16x32_bf16(A1, B[ct][1], acc[ct], 0, 0, 0);
  }
  // epilogue: store bf16 xl + attention scalars
  float p1[4] = {0.f,0.f,0.f,0.f}, p2[4] = {0.f,0.f,0.f,0.f};
  #pragma unroll
  for (int ct = 0; ct < 4; ++ct){
    const float wi = att_i[ct*16 + m], wj = att_j[ct*16 + m];
    #pragma unroll
    for (int reg = 0; reg < 4; ++reg){
      float v = acc[ct][reg];
      const int row = rw + quad*4 + reg;
      xl[(size_t)row*64 + ct*16 + m] = __float2bfloat16(v);
      p1[reg] = fmaf(v, wi, p1[reg]);
      p2[reg] = fmaf(v, wj, p2[reg]);
    }
  }
  #pragma unroll
  for (int reg = 0; reg < 4; ++reg){
    #pragma unroll
    for (int s = 1; s < 16; s <<= 1){
      p1[reg] += __shfl_xor(p1[reg], s, 16);
      p2[reg] += __shfl_xor(p2[reg], s, 16);
    }
    if (m == 0){
      const int r = rw + quad*4 + reg, node = r & 255;
      aip[r] = p1[reg] + emi[node];
      ajp[r] = p2[reg] + emj[node];
    }
  }
}

// ---------------- K3: edge softmax + gather aggregation + bn1 shadow stats (16 nodes/wave) ----------------
__global__ void __launch_bounds__(256) k_attn_agg(const int* __restrict__ topk,
                         const __hip_bfloat16* __restrict__ xl,
                         fpc aip, fpc ajp, fpc gnn_bias, float* __restrict__ agg,
                         float* __restrict__ bnsum){
  __shared__ float s_alpha[4][32];
  __shared__ int   s_src[4][32];
  __shared__ float s_ps[4][64], s_pq[4][64];
  const int t = threadIdx.x, w = t >> 6, lane = t & 63;
  const float bias = gnn_bias[lane];
  const int vbase = blockIdx.x*64 + w*16;    // 1024 blocks x 64 nodes; 16/wave
  float sum = 0.f, sq = 0.f;
  for (int j = 0; j < 16; ++j){
    const int v = vbase + j, i = v & 255, b = v >> 8;
    float lg = -1e30f; int sl = 0;
    if (lane < 21){
      sl = (lane < 20) ? topk[i*TK + lane] : i;
      if (lane == 20 || sl != i){            // remove_self_loops, keep appended loop
        float l = aip[v] + ajp[b*256 + sl];
        lg = (l >= 0.f) ? l : 0.2f*l;        // leaky_relu(0.2)
      }
    }
    float m = lg;
    for (int s = 1; s < 32; s <<= 1) m = fmaxf(m, __shfl_xor(m, s, 32));
    float e = (lg > -1e29f) ? __expf(lg - m) : 0.f;
    float den = e;
    for (int s = 1; s < 32; s <<= 1) den += __shfl_xor(den, s, 32);
    if (lane < 21){ s_alpha[w][lane] = e / den; s_src[w][lane] = b*256 + sl; }
    // same-wave LDS RAW: in-order per wave
    float acc = bias;
    #pragma unroll
    for (int k = 0; k < 21; ++k)
      acc = fmaf(s_alpha[w][k], __bfloat162float(xl[(size_t)s_src[w][k]*64 + lane]), acc);
    agg[(size_t)v*64 + lane] = acc;
    sum += acc; sq = fmaf(acc, acc, sq);
  }
  s_ps[w][lane] = sum; s_pq[w][lane] = sq;
  __syncthreads();
  if (t < 64){
    const int cp = (blockIdx.x & 7)*64;
    atomicAdd(&bnsum[cp + t],       s_ps[0][t] + s_ps[1][t] + s_ps[2][t] + s_ps[3][t]);
    atomicAdd(&bnsum[512 + cp + t], s_pq[0][t] + s_pq[1][t] + s_pq[2][t] + s_pq[3][t]);
  }
}

// ---------------- K4: bn1 finalize + ReLU in place (float4) + bn2 shadow stats ----------------
__global__ void __launch_bounds__(256) k_bn1_apply(float* __restrict__ agg, fpc emb, fpc g1, fpc be1,
                          float* __restrict__ bnsum){
  const int t = threadIdx.x, qc = t & 15, rs = t >> 4;
  float4 sc, sh;
  {
    float s[4], q[4];
    #pragma unroll
    for (int k = 0; k < 4; ++k){
      const int d = qc*4 + k;
      float S = 0.f, Q = 0.f;
      #pragma unroll
      for (int cp = 0; cp < 8; ++cp){ S += bnsum[cp*64 + d]; Q += bnsum[512 + cp*64 + d]; }
      float mean = S * (1.f/BN);
      float var  = Q * (1.f/BN) - mean*mean;
      s[k] = g1[d] * rsqrtf(var + 1e-5f);
      q[k] = be1[d] - mean*s[k];
    }
    sc = make_float4(s[0], s[1], s[2], s[3]);
    sh = make_float4(q[0], q[1], q[2], q[3]);
  }
  float4* agg4 = (float4*)agg;
  const float4* emb4 = (const float4*)emb;
  float4 ys = make_float4(0,0,0,0), yq = make_float4(0,0,0,0);
  const int rbase = blockIdx.x*32;           // 2048 blocks x 32 rows
  #pragma unroll
  for (int jj = 0; jj < 2; ++jj){
    const int r = rbase + jj*16 + rs;
    float4 x = agg4[(size_t)r*16 + qc];
    float4 g;
    g.x = fmaxf(fmaf(x.x, sc.x, sh.x), 0.f);
    g.y = fmaxf(fmaf(x.y, sc.y, sh.y), 0.f);
    g.z = fmaxf(fmaf(x.z, sc.z, sh.z), 0.f);
    g.w = fmaxf(fmaf(x.w, sc.w, sh.w), 0.f);
    agg4[(size_t)r*16 + qc] = g;             // gnn_out in place
    float4 e = emb4[(r & 255)*16 + qc];
    float4 y = make_float4(g.x*e.x, g.y*e.y, g.z*e.z, g.w*e.w);
    ys.x += y.x; ys.y += y.y; ys.z += y.z; ys.w += y.w;
    yq.x = fmaf(y.x, y.x, yq.x); yq.y = fmaf(y.y, y.y, yq.y);
    yq.z = fmaf(y.z, y.z, yq.z); yq.w = fmaf(y.w, y.w, yq.w);
  }
  __shared__ float4 s_s[16][16], s_q[16][16];
  s_s[rs][qc] = ys; s_q[rs][qc] = yq;
  __syncthreads();
  if (t < 64){
    const int qq = t >> 2, comp = t & 3;
    float S = 0.f, Q = 0.f;
    #pragma unroll
    for (int rr = 0; rr < 16; ++rr){
      S += ((const float*)&s_s[rr][qq])[comp];
      Q += ((const float*)&s_q[rr][qq])[comp];
    }
    const int cp = (blockIdx.x & 7)*64;
    atomicAdd(&bnsum[1024 + cp + t], S);
    atomicAdd(&bnsum[1536 + cp + t], Q);
  }
}

// ---------------- K5: encoder GEMM via MFMA; grid 128 kt-slices (K=128 each) ----------------
__global__ void __launch_bounds__(256) k_enc(const float* __restrict__ gnn, fpc enc_w,
                                             float* __restrict__ part){
  const int t = threadIdx.x, w = t >> 6, lane = t & 63;
  const int m = lane & 15, quad = lane >> 4;
  const int kt = blockIdx.x, kbase = kt*128;
  floatx4 acc[4][4];                          // [row-tile][col-tile]
  #pragma unroll
  for (int i = 0; i < 4; ++i)
    #pragma unroll
    for (int ct = 0; ct < 4; ++ct)
      acc[i][ct] = (floatx4){0.f, 0.f, 0.f, 0.f};

  for (int kc = 0; kc < 4; ++kc){
    const int kof = kbase + kc*32 + quad*8;
    short8 Bf[4];
    #pragma unroll
    for (int ct = 0; ct < 4; ++ct)
      #pragma unroll
      for (int j = 0; j < 8; ++j)
        Bf[ct][j] = f2b(enc_w[(size_t)(kof + j)*64 + ct*16 + m]);
    #pragma unroll
    for (int i = 0; i < 4; ++i){
      const int row = (w*4 + i)*16 + m;       // waves cover all 256 batch rows
      const float4* ap = (const float4*)(gnn + (size_t)row*16384 + kof);
      float4 q0 = ap[0], q1 = ap[1];
      short8 Af;
      Af[0]=f2b(q0.x); Af[1]=f2b(q0.y); Af[2]=f2b(q0.z); Af[3]=f2b(q0.w);
      Af[4]=f2b(q1.x); Af[5]=f2b(q1.y); Af[6]=f2b(q1.z); Af[7]=f2b(q1.w);
      #pragma unroll
      for (int ct = 0; ct < 4; ++ct)
        acc[i][ct] = __builtin_amdgcn_mfma_f32_16x16x32_bf16(Af, Bf[ct], acc[i][ct], 0, 0, 0);
    }
  }
  #pragma unroll
  for (int i = 0; i < 4; ++i)
    #pragma unroll
    for (int ct = 0; ct < 4; ++ct)
      #pragma unroll
      for (int reg = 0; reg < 4; ++reg){
        const int row = (w*4 + i)*16 + quad*4 + reg;
        part[(size_t)kt*16384 + row*64 + ct*16 + m] = acc[i][ct][reg];
      }
}

// ---------------- K5b: reduce split-K partials -> encoded ----------------
__global__ void __launch_bounds__(256) k_red(const float* __restrict__ part,
                                             float* __restrict__ encoded){
  const int idx = blockIdx.x*256 + threadIdx.x;   // 64 blocks x 256 = 16384
  float s = 0.f;
  #pragma unroll 8
  for (int kt = 0; kt < 128; ++kt) s += part[(size_t)kt*16384 + idx];
  encoded[idx] = s;
}

// ---------------- K6: score head (float4, width-16 reduce) + arrangement in block 0 ----------------
__global__ void __launch_bounds__(256) k_score(const float* __restrict__ gnn, fpc emb, fpc g2, fpc be2,
                      const float* __restrict__ bnsum, fpc out_w, fpc out_b,
                      const float* __restrict__ encoded, fpc enc_b, fpc arr_w, fpc arr_b,
                      float* __restrict__ out){
  const int t = threadIdx.x, w = t >> 6, lane = t & 63;
  const int qc = lane & 15, rq = lane >> 4;
  float sc2[4], sh2[4], ow[4];
  #pragma unroll
  for (int k = 0; k < 4; ++k){
    const int d = qc*4 + k;
    float S = 0.f, Q = 0.f;
    #pragma unroll
    for (int cp = 0; cp < 8; ++cp){ S += bnsum[1024 + cp*64 + d]; Q += bnsum[1536 + cp*64 + d]; }
    float mean = S * (1.f/BN);
    float var  = Q * (1.f/BN) - mean*mean;
    sc2[k] = g2[d] * rsqrtf(var + 1e-5f);
    sh2[k] = be2[d] - mean*sc2[k];
    ow[k]  = out_w[d];
  }
  const float ob = out_b[0];
  const float4* gnn4 = (const float4*)gnn;
  const float4* emb4 = (const float4*)emb;
  const int base = blockIdx.x*32 + w*8;      // 2048 blocks x 32 rows
  #pragma unroll
  for (int it = 0; it < 2; ++it){
    const int r = base + it*4 + rq;
    float4 y4 = gnn4[(size_t)r*16 + qc];
    float4 e4 = emb4[(r & 255)*16 + qc];
    float p = 0.f, yh;
    yh = fmaxf(fmaf(y4.x*e4.x, sc2[0], sh2[0]), 0.f); p = fmaf(yh, ow[0], p);
    yh = fmaxf(fmaf(y4.y*e4.y, sc2[1], sh2[1]), 0.f); p = fmaf(yh, ow[1], p);
    yh = fmaxf(fmaf(y4.z*e4.z, sc2[2], sh2[2]), 0.f); p = fmaf(yh, ow[2], p);
    yh = fmaxf(fmaf(y4.w*e4.w, sc2[3], sh2[3]), 0.f); p = fmaf(yh, ow[3], p);
    #pragma unroll
    for (int mm = 1; mm < 16; mm <<= 1) p += __shfl_xor(p, mm, 16);
    if (qc == 0) out[r] = p + ob;
  }
  if (blockIdx.x == 0){
    const int b = t;
    float o[7];
    #pragma unroll
    for (int j = 0; j < 7; ++j) o[j] = arr_b[j];
    for (int c = 0; c < 64; ++c){
      float e = encoded[b*64 + c] + enc_b[c];
      #pragma unroll
      for (int j = 0; j < 7; ++j) o[j] = fmaf(e, arr_w[c*7 + j], o[j]);
    }
    #pragma unroll
    for (int j = 0; j < 7; ++j) out[65536 + b*7 + j] = o[j];
  }
}

extern "C" void kernel_launch(void* const* d_in, const int* in_sizes, int n_in,
                              void* d_out, int out_size, void* d_ws, size_t ws_size,
                              hipStream_t stream) {
  fpc data     = (fpc)d_in[0];
  fpc emb      = (fpc)d_in[1];
  fpc lin_w    = (fpc)d_in[2];
  fpc att_i    = (fpc)d_in[3];
  fpc att_j    = (fpc)d_in[4];
  fpc att_em_i = (fpc)d_in[5];
  fpc att_em_j = (fpc)d_in[6];
  fpc gnn_bias = (fpc)d_in[7];
  fpc g1       = (fpc)d_in[8];
  fpc be1      = (fpc)d_in[9];
  fpc g2       = (fpc)d_in[10];
  fpc be2      = (fpc)d_in[11];
  fpc enc_w    = (fpc)d_in[12];
  fpc enc_b    = (fpc)d_in[13];
  fpc arr_w    = (fpc)d_in[14];
  fpc arr_b    = (fpc)d_in[15];
  fpc out_w    = (fpc)d_in[16];
  fpc out_b    = (fpc)d_in[17];

  float* fw = (float*)d_ws;
  int*   topk    = (int*)d_ws;            // [0, 5120)
  float* emi     = fw + 5120;             // 256
  float* emj     = fw + 5376;             // 256
  float* bnsum   = fw + 5632;             // 2048 shadow BN accumulators (memset below)
  float* encoded = fw + 7680;             // 16384
  float* aip     = fw + 24064;            // 65536
  float* ajp     = fw + 89600;            // 65536
  float* agg     = fw + 155136;           // 65536*64 f32 (becomes gnn_out in place)
  __hip_bfloat16* xl = (__hip_bfloat16*)(fw + 4349440);  // 65536*64 bf16 = 8.39 MB
  float* part    = (float*)xl;            // 128*16384 f32 = 8.39 MB, aliases dead xl (order-separated)
  float* out     = (float*)d_out;

  hipMemsetAsync((void*)bnsum, 0, 2048u*sizeof(float), stream);

  k_graph    <<<256,   256, 0, stream>>>(emb, att_em_i, att_em_j, topk, emi, emj);
  k_xl       <<<1024,  256, 0, stream>>>(data, lin_w, att_i, att_j, emi, emj, xl, aip, ajp);
  k_attn_agg <<<1024,  256, 0, stream>>>(topk, xl, aip, ajp, gnn_bias, agg, bnsum);
  k_bn1_apply<<<2048,  256, 0, stream>>>(agg, emb, g1, be1, bnsum);
  k_enc      <<<128,   256, 0, stream>>>(agg, enc_w, part);
  k_red      <<<64,    256, 0, stream>>>(part, encoded);
  k_score    <<<2048,  256, 0, stream>>>(agg, emb, g2, be2, bnsum, out_w, out_b,
                                         encoded, enc_b, arr_w, arr_b, out);
}

// Round 11
// 188.674 us; speedup vs baseline: 1.9085x; 1.0090x over previous
//
#include <hip/hip_runtime.h>
#include <hip/hip_bf16.h>

#define TK 20
#define BN 65536

typedef const float* fpc;
typedef __attribute__((ext_vector_type(8))) short short8;
typedef __attribute__((ext_vector_type(4))) float floatx4;

// f32 -> bf16 bits, round-to-nearest-even
__device__ __forceinline__ short f2b(float f){
  unsigned u = __float_as_uint(f);
  return (short)((u + 0x7fffu + ((u >> 16) & 1u)) >> 16);
}

// ---------------- K1: top-20 cosine graph + emi/emj ----------------
__global__ void k_graph(fpc emb, fpc att_em_i, fpc att_em_j,
                        int* __restrict__ topk, float* __restrict__ emi, float* __restrict__ emj){
  __shared__ float s_cos[256];
  __shared__ float s_wi[64];
  const int i = blockIdx.x;
  const int t = threadIdx.x;
  if (t < 64) s_wi[t] = emb[i*64 + t];
  __syncthreads();
  float dot = 0.f, nj = 0.f, ni = 0.f;
  for (int f = 0; f < 64; ++f){
    float wj = emb[t*64 + f], wi = s_wi[f];
    dot = fmaf(wi, wj, dot); nj = fmaf(wj, wj, nj); ni = fmaf(wi, wi, ni);
  }
  s_cos[t] = dot / (sqrtf(ni) * sqrtf(nj));
  __syncthreads();

  if (t < 64){
    // wave 0: 20 rounds of argmax (tie -> lower index) over 256 values
    float v0 = s_cos[t], v1 = s_cos[t+64], v2 = s_cos[t+128], v3 = s_cos[t+192];
    int taken = 0;
    for (int r = 0; r < TK; ++r){
      float bv = (taken & 1) ? -3.f : v0; int bi = t;
      float c;
      c = (taken & 2) ? -3.f : v1; if (c > bv){ bv = c; bi = t+64;  }
      c = (taken & 4) ? -3.f : v2; if (c > bv){ bv = c; bi = t+128; }
      c = (taken & 8) ? -3.f : v3; if (c > bv){ bv = c; bi = t+192; }
      for (int m = 1; m < 64; m <<= 1){
        float ov = __shfl_xor(bv, m, 64);
        int   oi = __shfl_xor(bi, m, 64);
        if (ov > bv || (ov == bv && oi < bi)){ bv = ov; bi = oi; }
      }
      if (t == 0) topk[i*TK + r] = bi;
      if ((bi & 63) == t) taken |= 1 << (bi >> 6);
    }
  } else if (t < 128){
    int d = t - 64;
    float wv = s_wi[d];
    float p1 = wv * att_em_i[d];
    float p2 = wv * att_em_j[d];
    for (int m = 1; m < 64; m <<= 1){
      p1 += __shfl_xor(p1, m, 64);
      p2 += __shfl_xor(p2, m, 64);
    }
    if (d == 0){ emi[i] = p1; emj[i] = p2; }
  }
}

// ---------------- K2: xl = data @ lin_w via MFMA 16x16x32 bf16 + aip/ajp ----------------
__global__ void __launch_bounds__(256) k_xl(fpc data, fpc lin_w, fpc att_i, fpc att_j,
                     fpc emi, fpc emj,
                     __hip_bfloat16* __restrict__ xl,
                     float* __restrict__ aip, float* __restrict__ ajp){
  const int t = threadIdx.x, w = t >> 6, lane = t & 63;
  const int m = lane & 15, quad = lane >> 4;
  short8 B[4][2];
  #pragma unroll
  for (int ct = 0; ct < 4; ++ct)
    #pragma unroll
    for (int kc = 0; kc < 2; ++kc)
      #pragma unroll
      for (int j = 0; j < 8; ++j)
        B[ct][kc][j] = f2b(lin_w[(kc*32 + quad*8 + j)*64 + ct*16 + m]);

  const int rw = blockIdx.x*64 + w*16;       // 1024 blocks x 64 rows; wave = 16-row tile
  short8 A0, A1;
  {
    const float4* ap0 = (const float4*)(data + (size_t)(rw + m)*64 + quad*8);
    float4 q0 = ap0[0], q1 = ap0[1];
    A0[0]=f2b(q0.x); A0[1]=f2b(q0.y); A0[2]=f2b(q0.z); A0[3]=f2b(q0.w);
    A0[4]=f2b(q1.x); A0[5]=f2b(q1.y); A0[6]=f2b(q1.z); A0[7]=f2b(q1.w);
    const float4* ap1 = (const float4*)(data + (size_t)(rw + m)*64 + 32 + quad*8);
    float4 q2 = ap1[0], q3 = ap1[1];
    A1[0]=f2b(q2.x); A1[1]=f2b(q2.y); A1[2]=f2b(q2.z); A1[3]=f2b(q2.w);
    A1[4]=f2b(q3.x); A1[5]=f2b(q3.y); A1[6]=f2b(q3.z); A1[7]=f2b(q3.w);
  }
  floatx4 acc[4];
  #pragma unroll
  for (int ct = 0; ct < 4; ++ct){
    floatx4 z = {0.f, 0.f, 0.f, 0.f};
    acc[ct] = __builtin_amdgcn_mfma_f32_16x16x32_bf16(A0, B[ct][0], z, 0, 0, 0);
    acc[ct] = __builtin_amdgcn_mfma_f32_16x16x32_bf16(A1, B[ct][1], acc[ct], 0, 0, 0);
  }
  float p1[4] = {0.f,0.f,0.f,0.f}, p2[4] = {0.f,0.f,0.f,0.f};
  #pragma unroll
  for (int ct = 0; ct < 4; ++ct){
    const float wi = att_i[ct*16 + m], wj = att_j[ct*16 + m];
    #pragma unroll
    for (int reg = 0; reg < 4; ++reg){
      float v = acc[ct][reg];
      const int row = rw + quad*4 + reg;
      xl[(size_t)row*64 + ct*16 + m] = __float2bfloat16(v);
      p1[reg] = fmaf(v, wi, p1[reg]);
      p2[reg] = fmaf(v, wj, p2[reg]);
    }
  }
  #pragma unroll
  for (int reg = 0; reg < 4; ++reg){
    #pragma unroll
    for (int s = 1; s < 16; s <<= 1){
      p1[reg] += __shfl_xor(p1[reg], s, 16);
      p2[reg] += __shfl_xor(p2[reg], s, 16);
    }
    if (m == 0){
      const int r = rw + quad*4 + reg, node = r & 255;
      aip[r] = p1[reg] + emi[node];
      ajp[r] = p2[reg] + emj[node];
    }
  }
}

// ---------------- K3: edge softmax + gather aggregation + bn1 shadow stats ----------------
__global__ void __launch_bounds__(256) k_attn_agg(const int* __restrict__ topk,
                         const __hip_bfloat16* __restrict__ xl,
                         fpc aip, fpc ajp, fpc gnn_bias, float* __restrict__ agg,
                         float* __restrict__ bnsum){
  __shared__ float s_alpha[4][32];
  __shared__ int   s_src[4][32];
  __shared__ float s_ps[4][64], s_pq[4][64];
  const int t = threadIdx.x, w = t >> 6, lane = t & 63;
  const float bias = gnn_bias[lane];
  const int vbase = blockIdx.x*64 + w*16;    // 1024 blocks x 64 nodes; 16/wave
  float sum = 0.f, sq = 0.f;
  for (int j = 0; j < 16; ++j){
    const int v = vbase + j, i = v & 255, b = v >> 8;
    float lg = -1e30f; int sl = 0;
    if (lane < 21){
      sl = (lane < 20) ? topk[i*TK + lane] : i;
      if (lane == 20 || sl != i){            // remove_self_loops, keep appended loop
        float l = aip[v] + ajp[b*256 + sl];
        lg = (l >= 0.f) ? l : 0.2f*l;        // leaky_relu(0.2)
      }
    }
    float m = lg;
    for (int s = 1; s < 32; s <<= 1) m = fmaxf(m, __shfl_xor(m, s, 32));
    float e = (lg > -1e29f) ? __expf(lg - m) : 0.f;
    float den = e;
    for (int s = 1; s < 32; s <<= 1) den += __shfl_xor(den, s, 32);
    if (lane < 21){ s_alpha[w][lane] = e / den; s_src[w][lane] = b*256 + sl; }
    float acc = bias;
    #pragma unroll
    for (int k = 0; k < 21; ++k)
      acc = fmaf(s_alpha[w][k], __bfloat162float(xl[(size_t)s_src[w][k]*64 + lane]), acc);
    agg[(size_t)v*64 + lane] = acc;
    sum += acc; sq = fmaf(acc, acc, sq);
  }
  s_ps[w][lane] = sum; s_pq[w][lane] = sq;
  __syncthreads();
  if (t < 64){
    const int cp = (blockIdx.x & 7)*64;
    atomicAdd(&bnsum[cp + t],       s_ps[0][t] + s_ps[1][t] + s_ps[2][t] + s_ps[3][t]);
    atomicAdd(&bnsum[512 + cp + t], s_pq[0][t] + s_pq[1][t] + s_pq[2][t] + s_pq[3][t]);
  }
}

// ---------------- K4: bn2 stats only -- read-only pass over raw agg (bn1 applied on the fly) ----------------
__global__ void __launch_bounds__(256) k_stats2(const float* __restrict__ agg, fpc emb, fpc g1, fpc be1,
                          float* __restrict__ bnsum){
  const int t = threadIdx.x, qc = t & 15, rs = t >> 4;
  float4 sc, sh;
  {
    float s[4], q[4];
    #pragma unroll
    for (int k = 0; k < 4; ++k){
      const int d = qc*4 + k;
      float S = 0.f, Q = 0.f;
      #pragma unroll
      for (int cp = 0; cp < 8; ++cp){ S += bnsum[cp*64 + d]; Q += bnsum[512 + cp*64 + d]; }
      float mean = S * (1.f/BN);
      float var  = Q * (1.f/BN) - mean*mean;
      s[k] = g1[d] * rsqrtf(var + 1e-5f);
      q[k] = be1[d] - mean*s[k];
    }
    sc = make_float4(s[0], s[1], s[2], s[3]);
    sh = make_float4(q[0], q[1], q[2], q[3]);
  }
  const float4* agg4 = (const float4*)agg;
  const float4* emb4 = (const float4*)emb;
  float4 ys = make_float4(0,0,0,0), yq = make_float4(0,0,0,0);
  const int rbase = blockIdx.x*32;           // 2048 blocks x 32 rows
  #pragma unroll
  for (int jj = 0; jj < 2; ++jj){
    const int r = rbase + jj*16 + rs;
    float4 x = agg4[(size_t)r*16 + qc];
    float4 e = emb4[(r & 255)*16 + qc];
    float4 y;
    y.x = fmaxf(fmaf(x.x, sc.x, sh.x), 0.f) * e.x;
    y.y = fmaxf(fmaf(x.y, sc.y, sh.y), 0.f) * e.y;
    y.z = fmaxf(fmaf(x.z, sc.z, sh.z), 0.f) * e.z;
    y.w = fmaxf(fmaf(x.w, sc.w, sh.w), 0.f) * e.w;
    ys.x += y.x; ys.y += y.y; ys.z += y.z; ys.w += y.w;
    yq.x = fmaf(y.x, y.x, yq.x); yq.y = fmaf(y.y, y.y, yq.y);
    yq.z = fmaf(y.z, y.z, yq.z); yq.w = fmaf(y.w, y.w, yq.w);
  }
  __shared__ float4 s_s[16][16], s_q[16][16];
  s_s[rs][qc] = ys; s_q[rs][qc] = yq;
  __syncthreads();
  if (t < 64){
    const int qq = t >> 2, comp = t & 3;
    float S = 0.f, Q = 0.f;
    #pragma unroll
    for (int rr = 0; rr < 16; ++rr){
      S += ((const float*)&s_s[rr][qq])[comp];
      Q += ((const float*)&s_q[rr][qq])[comp];
    }
    const int cp = (blockIdx.x & 7)*64;
    atomicAdd(&bnsum[1024 + cp + t], S);
    atomicAdd(&bnsum[1536 + cp + t], Q);
  }
}

// ---------------- K5: encoder GEMM via MFMA, bn1+relu applied at load; grid (128 kt, 2 bt) ----------------
__global__ void __launch_bounds__(256) k_enc(const float* __restrict__ agg, fpc enc_w,
                                             fpc g1, fpc be1, const float* __restrict__ bnsum,
                                             float* __restrict__ part){
  const int t = threadIdx.x, w = t >> 6, lane = t & 63;
  const int m = lane & 15, quad = lane >> 4;
  const int kt = blockIdx.x, bt = blockIdx.y, kbase = kt*128;
  // bn1 constants for this lane's channels: chA = quad*8+j (kc even), chB = 32+quad*8+j (kc odd)
  float scA[8], shA[8], scB[8], shB[8];
  #pragma unroll
  for (int j = 0; j < 8; ++j){
    #pragma unroll
    for (int par = 0; par < 2; ++par){
      const int d = par*32 + quad*8 + j;
      float S = 0.f, Q = 0.f;
      #pragma unroll
      for (int cp = 0; cp < 8; ++cp){ S += bnsum[cp*64 + d]; Q += bnsum[512 + cp*64 + d]; }
      float mean = S * (1.f/BN);
      float var  = Q * (1.f/BN) - mean*mean;
      float sc = g1[d] * rsqrtf(var + 1e-5f);
      float sh = be1[d] - mean*sc;
      if (par == 0){ scA[j] = sc; shA[j] = sh; } else { scB[j] = sc; shB[j] = sh; }
    }
  }
  floatx4 acc[2][4];                          // [row-tile][col-tile]
  #pragma unroll
  for (int i = 0; i < 2; ++i)
    #pragma unroll
    for (int ct = 0; ct < 4; ++ct)
      acc[i][ct] = (floatx4){0.f, 0.f, 0.f, 0.f};

  #pragma unroll
  for (int kc = 0; kc < 4; ++kc){
    const int kof = kbase + kc*32 + quad*8;
    const bool odd = (kc & 1);
    short8 Bf[4];
    #pragma unroll
    for (int ct = 0; ct < 4; ++ct)
      #pragma unroll
      for (int j = 0; j < 8; ++j)
        Bf[ct][j] = f2b(enc_w[(size_t)(kof + j)*64 + ct*16 + m]);
    #pragma unroll
    for (int i = 0; i < 2; ++i){
      const int row = bt*128 + (w*2 + i)*16 + m;
      const float4* ap = (const float4*)(agg + (size_t)row*16384 + kof);
      float4 q0 = ap[0], q1 = ap[1];
      short8 Af;
      if (!odd){
        Af[0]=f2b(fmaxf(fmaf(q0.x, scA[0], shA[0]), 0.f));
        Af[1]=f2b(fmaxf(fmaf(q0.y, scA[1], shA[1]), 0.f));
        Af[2]=f2b(fmaxf(fmaf(q0.z, scA[2], shA[2]), 0.f));
        Af[3]=f2b(fmaxf(fmaf(q0.w, scA[3], shA[3]), 0.f));
        Af[4]=f2b(fmaxf(fmaf(q1.x, scA[4], shA[4]), 0.f));
        Af[5]=f2b(fmaxf(fmaf(q1.y, scA[5], shA[5]), 0.f));
        Af[6]=f2b(fmaxf(fmaf(q1.z, scA[6], shA[6]), 0.f));
        Af[7]=f2b(fmaxf(fmaf(q1.w, scA[7], shA[7]), 0.f));
      } else {
        Af[0]=f2b(fmaxf(fmaf(q0.x, scB[0], shB[0]), 0.f));
        Af[1]=f2b(fmaxf(fmaf(q0.y, scB[1], shB[1]), 0.f));
        Af[2]=f2b(fmaxf(fmaf(q0.z, scB[2], shB[2]), 0.f));
        Af[3]=f2b(fmaxf(fmaf(q0.w, scB[3], shB[3]), 0.f));
        Af[4]=f2b(fmaxf(fmaf(q1.x, scB[4], shB[4]), 0.f));
        Af[5]=f2b(fmaxf(fmaf(q1.y, scB[5], shB[5]), 0.f));
        Af[6]=f2b(fmaxf(fmaf(q1.z, scB[6], shB[6]), 0.f));
        Af[7]=f2b(fmaxf(fmaf(q1.w, scB[7], shB[7]), 0.f));
      }
      #pragma unroll
      for (int ct = 0; ct < 4; ++ct)
        acc[i][ct] = __builtin_amdgcn_mfma_f32_16x16x32_bf16(Af, Bf[ct], acc[i][ct], 0, 0, 0);
    }
  }
  #pragma unroll
  for (int i = 0; i < 2; ++i)
    #pragma unroll
    for (int ct = 0; ct < 4; ++ct)
      #pragma unroll
      for (int reg = 0; reg < 4; ++reg){
        const int row = bt*128 + (w*2 + i)*16 + quad*4 + reg;
        part[(size_t)kt*16384 + row*64 + ct*16 + m] = acc[i][ct][reg];
      }
}

// ---------------- K5b: reduce split-K partials + arrangement head (block = batch row) ----------------
__global__ void __launch_bounds__(256) k_redarr(const float* __restrict__ part,
                      fpc enc_b, fpc arr_w, fpc arr_b, float* __restrict__ out){
  __shared__ float s_enc[4][64];
  const int b = blockIdx.x, t = threadIdx.x, w = t >> 6, lane = t & 63;
  float s = 0.f;
  #pragma unroll 8
  for (int k = 0; k < 32; ++k)
    s += part[(size_t)(w*32 + k)*16384 + b*64 + lane];
  s_enc[w][lane] = s;
  __syncthreads();
  if (t < 64){
    float e = s_enc[0][t] + s_enc[1][t] + s_enc[2][t] + s_enc[3][t] + enc_b[t];
    float o[7];
    #pragma unroll
    for (int j = 0; j < 7; ++j) o[j] = e * arr_w[t*7 + j];
    #pragma unroll
    for (int j = 0; j < 7; ++j)
      #pragma unroll
      for (int m = 1; m < 64; m <<= 1) o[j] += __shfl_xor(o[j], m, 64);
    if (t == 0){
      #pragma unroll
      for (int j = 0; j < 7; ++j) out[65536 + b*7 + j] = o[j] + arr_b[j];
    }
  }
}

// ---------------- K6: score head -- bn1+bn2 applied on the fly from raw agg ----------------
__global__ void __launch_bounds__(256) k_score(const float* __restrict__ agg, fpc emb,
                      fpc g1, fpc be1, fpc g2, fpc be2,
                      const float* __restrict__ bnsum, fpc out_w, fpc out_b,
                      float* __restrict__ out){
  const int t = threadIdx.x, w = t >> 6, lane = t & 63;
  const int qc = lane & 15, rq = lane >> 4;
  float sc1[4], sh1[4], sc2[4], sh2[4], ow[4];
  #pragma unroll
  for (int k = 0; k < 4; ++k){
    const int d = qc*4 + k;
    float S1 = 0.f, Q1 = 0.f, S2 = 0.f, Q2 = 0.f;
    #pragma unroll
    for (int cp = 0; cp < 8; ++cp){
      S1 += bnsum[cp*64 + d];        Q1 += bnsum[512 + cp*64 + d];
      S2 += bnsum[1024 + cp*64 + d]; Q2 += bnsum[1536 + cp*64 + d];
    }
    float m1 = S1 * (1.f/BN), v1 = Q1 * (1.f/BN) - m1*m1;
    sc1[k] = g1[d] * rsqrtf(v1 + 1e-5f);
    sh1[k] = be1[d] - m1*sc1[k];
    float m2 = S2 * (1.f/BN), v2 = Q2 * (1.f/BN) - m2*m2;
    sc2[k] = g2[d] * rsqrtf(v2 + 1e-5f);
    sh2[k] = be2[d] - m2*sc2[k];
    ow[k]  = out_w[d];
  }
  const float ob = out_b[0];
  const float4* agg4 = (const float4*)agg;
  const float4* emb4 = (const float4*)emb;
  const int base = blockIdx.x*32 + w*8;      // 2048 blocks x 32 rows
  #pragma unroll
  for (int it = 0; it < 2; ++it){
    const int r = base + it*4 + rq;
    float4 x4 = agg4[(size_t)r*16 + qc];
    float4 e4 = emb4[(r & 255)*16 + qc];
    float p = 0.f, g, y, yh;
    g = fmaxf(fmaf(x4.x, sc1[0], sh1[0]), 0.f); y = g*e4.x;
    yh = fmaxf(fmaf(y, sc2[0], sh2[0]), 0.f); p = fmaf(yh, ow[0], p);
    g = fmaxf(fmaf(x4.y, sc1[1], sh1[1]), 0.f); y = g*e4.y;
    yh = fmaxf(fmaf(y, sc2[1], sh2[1]), 0.f); p = fmaf(yh, ow[1], p);
    g = fmaxf(fmaf(x4.z, sc1[2], sh1[2]), 0.f); y = g*e4.z;
    yh = fmaxf(fmaf(y, sc2[2], sh2[2]), 0.f); p = fmaf(yh, ow[2], p);
    g = fmaxf(fmaf(x4.w, sc1[3], sh1[3]), 0.f); y = g*e4.w;
    yh = fmaxf(fmaf(y, sc2[3], sh2[3]), 0.f); p = fmaf(yh, ow[3], p);
    #pragma unroll
    for (int mm = 1; mm < 16; mm <<= 1) p += __shfl_xor(p, mm, 16);
    if (qc == 0) out[r] = p + ob;
  }
}

extern "C" void kernel_launch(void* const* d_in, const int* in_sizes, int n_in,
                              void* d_out, int out_size, void* d_ws, size_t ws_size,
                              hipStream_t stream) {
  fpc data     = (fpc)d_in[0];
  fpc emb      = (fpc)d_in[1];
  fpc lin_w    = (fpc)d_in[2];
  fpc att_i    = (fpc)d_in[3];
  fpc att_j    = (fpc)d_in[4];
  fpc att_em_i = (fpc)d_in[5];
  fpc att_em_j = (fpc)d_in[6];
  fpc gnn_bias = (fpc)d_in[7];
  fpc g1       = (fpc)d_in[8];
  fpc be1      = (fpc)d_in[9];
  fpc g2       = (fpc)d_in[10];
  fpc be2      = (fpc)d_in[11];
  fpc enc_w    = (fpc)d_in[12];
  fpc enc_b    = (fpc)d_in[13];
  fpc arr_w    = (fpc)d_in[14];
  fpc arr_b    = (fpc)d_in[15];
  fpc out_w    = (fpc)d_in[16];
  fpc out_b    = (fpc)d_in[17];

  float* fw = (float*)d_ws;
  int*   topk    = (int*)d_ws;            // [0, 5120)
  float* emi     = fw + 5120;             // 256
  float* emj     = fw + 5376;             // 256
  float* bnsum   = fw + 5632;             // 2048 shadow BN accumulators (memset below)
  float* aip     = fw + 7680;             // 65536
  float* ajp     = fw + 73216;            // 65536
  float* agg     = fw + 138752;           // 65536*64 f32 (stays RAW attn output)
  __hip_bfloat16* xl = (__hip_bfloat16*)(fw + 4333056);  // 65536*64 bf16 = 8.39 MB
  float* part    = (float*)xl;            // 128*16384 f32 = 8.39 MB, aliases dead xl
  float* out     = (float*)d_out;

  hipMemsetAsync((void*)bnsum, 0, 2048u*sizeof(float), stream);

  k_graph    <<<256,   256, 0, stream>>>(emb, att_em_i, att_em_j, topk, emi, emj);
  k_xl       <<<1024,  256, 0, stream>>>(data, lin_w, att_i, att_j, emi, emj, xl, aip, ajp);
  k_attn_agg <<<1024,  256, 0, stream>>>(topk, xl, aip, ajp, gnn_bias, agg, bnsum);
  k_stats2   <<<2048,  256, 0, stream>>>(agg, emb, g1, be1, bnsum);
  k_enc      <<<dim3(128,2), 256, 0, stream>>>(agg, enc_w, g1, be1, bnsum, part);
  k_redarr   <<<256,   256, 0, stream>>>(part, enc_b, arr_w, arr_b, out);
  k_score    <<<2048,  256, 0, stream>>>(agg, emb, g1, be1, g2, be2, bnsum, out_w, out_b, out);
}